// Round 1
// baseline (275.901 us; speedup 1.0000x reference)
//
#include <hip/hip_runtime.h>
#include <stdint.h>

#define NH 16
#define NDV 64
#define NDM 1024
#define NB 8
#define NL 1024

typedef __attribute__((ext_vector_type(8))) short short8;
typedef __attribute__((ext_vector_type(4))) short short4v;
typedef __attribute__((ext_vector_type(4))) float f32x4;

static __device__ __forceinline__ unsigned short f2bf(float x) {
    unsigned int u = __builtin_bit_cast(unsigned int, x);
    unsigned int r = (u + 0x7fffu + ((u >> 16) & 1u)) >> 16;
    return (unsigned short)r;
}

static __device__ __forceinline__ float waveMax(float v) {
#pragma unroll
    for (int o = 32; o > 0; o >>= 1) v = fmaxf(v, __shfl_xor(v, o, 64));
    return v;
}
static __device__ __forceinline__ float waveSum(float v) {
#pragma unroll
    for (int o = 32; o > 0; o >>= 1) v += __shfl_xor(v, o, 64);
    return v;
}

// ---------------- fp32 -> bf16 convert (vectorized) ----------------
__global__ __launch_bounds__(256) void cvt_bf16(const float* __restrict__ src,
                                                unsigned short* __restrict__ dst) {
    const size_t idx = ((size_t)blockIdx.x * 256 + threadIdx.x) << 2;
    const float4 v = *(const float4*)(src + idx);
    short4v u;
    u[0] = (short)f2bf(v.x); u[1] = (short)f2bf(v.y);
    u[2] = (short)f2bf(v.z); u[3] = (short)f2bf(v.w);
    *(short4v*)(dst + idx) = u;
}

// ---------------- softmax of posi_att rows + replicate 8x + bf16 copy ----------------
// block = one (h, i) row; 256 threads * 4 floats
__global__ __launch_bounds__(256) void softmax_rep(const float* __restrict__ posi,
                                                   float* __restrict__ attn_out,
                                                   unsigned short* __restrict__ a_bf) {
    __shared__ float red[8];
    const int blk = blockIdx.x;
    const int h = blk >> 10, i = blk & 1023;
    const int t = threadIdx.x;
    const float4* rowp = (const float4*)(posi + (((size_t)h << 10) + i) * 1024);
    float4 p = rowp[t];
    const int j0 = t << 2;
    float* pf = (float*)&p;
    if (i >= j0 && i < j0 + 4) pf[i - j0] = -1e30f;  // mask diagonal
    float m = fmaxf(fmaxf(pf[0], pf[1]), fmaxf(pf[2], pf[3]));
    m = waveMax(m);
    if ((t & 63) == 0) red[t >> 6] = m;
    __syncthreads();
    m = fmaxf(fmaxf(red[0], red[1]), fmaxf(red[2], red[3]));
    const float e0 = __expf(pf[0] - m), e1 = __expf(pf[1] - m);
    const float e2 = __expf(pf[2] - m), e3 = __expf(pf[3] - m);
    float s = waveSum(e0 + e1 + e2 + e3);
    if ((t & 63) == 0) red[4 + (t >> 6)] = s;
    __syncthreads();
    s = red[4] + red[5] + red[6] + red[7];
    const float inv = 1.0f / s;
    float4 a;
    a.x = e0 * inv; a.y = e1 * inv; a.z = e2 * inv; a.w = e3 * inv;
    // replicate to attn_out[(h*8+b, i, :)] for b=0..7
    float* base = attn_out + (((size_t)h << 3) << 20) + ((size_t)i << 10);
#pragma unroll
    for (int b = 0; b < 8; ++b)
        ((float4*)(base + ((size_t)b << 20)))[t] = a;
    // bf16 copy of A[h][i][:] for the PV GEMM
    short4v u;
    u[0] = (short)f2bf(a.x); u[1] = (short)f2bf(a.y);
    u[2] = (short)f2bf(a.z); u[3] = (short)f2bf(a.w);
    *(short4v*)(a_bf + ((((size_t)h << 10) + i) << 10) + j0) = u;
}

// ---------------- bf16 MFMA GEMM: C[M,N] = A[M,K] @ Bt[N,K]^T ----------------
// 128x128 tile, 4 waves (2x2), each wave 64x64 via 4x4 mfma_f32_16x16x32_bf16.
// EPI=1: +bias, store bf16 scattered to vvT[h][b*64+d][l]
// EPI=2: store bf16 scattered to X[(b*1024+q)][h*64+d]   (batched over h = blockIdx.z)
// EPI=3: +bias, store fp32 row-major
template <int EPI>
__global__ __launch_bounds__(256) void gemm_bt(const unsigned short* __restrict__ A,
                                               const unsigned short* __restrict__ Bt,
                                               const float* __restrict__ bias,
                                               void* __restrict__ Cout,
                                               int M, int N, int K) {
    __shared__ unsigned short sA[128 * 40];  // +8 pad: 80B row stride -> 2-way (free) conflicts
    __shared__ unsigned short sB[128 * 40];
    const int tid = threadIdx.x;
    const int lane = tid & 63;
    const int w = tid >> 6;
    const int wr = w >> 1, wc = w & 1;
    const int tn = blockIdx.x, tm = blockIdx.y, bh = blockIdx.z;

    const unsigned short* Ab = A;
    const unsigned short* Bb = Bt;
    if (EPI == 2) { Ab += (size_t)bh * 1048576; Bb += (size_t)bh * 524288; }
    Ab += (size_t)tm * 128 * K;
    Bb += (size_t)tn * 128 * K;

    const int srow = tid >> 2;
    const int scol = (tid & 3) * 8;

    f32x4 acc[4][4];
#pragma unroll
    for (int i = 0; i < 4; ++i)
#pragma unroll
        for (int j = 0; j < 4; ++j) acc[i][j] = (f32x4){0.f, 0.f, 0.f, 0.f};

    for (int kt = 0; kt < K; kt += 32) {
        __syncthreads();
        short8 a0 = *(const short8*)(Ab + (size_t)srow * K + kt + scol);
        short8 a1 = *(const short8*)(Ab + (size_t)(srow + 64) * K + kt + scol);
        short8 b0 = *(const short8*)(Bb + (size_t)srow * K + kt + scol);
        short8 b1 = *(const short8*)(Bb + (size_t)(srow + 64) * K + kt + scol);
        *(short8*)&sA[srow * 40 + scol] = a0;
        *(short8*)&sA[(srow + 64) * 40 + scol] = a1;
        *(short8*)&sB[srow * 40 + scol] = b0;
        *(short8*)&sB[(srow + 64) * 40 + scol] = b1;
        __syncthreads();

        short8 af[4], bfr[4];
#pragma unroll
        for (int f = 0; f < 4; ++f)
            af[f] = *(const short8*)&sA[(wr * 64 + f * 16 + (lane & 15)) * 40 + (lane >> 4) * 8];
#pragma unroll
        for (int f = 0; f < 4; ++f)
            bfr[f] = *(const short8*)&sB[(wc * 64 + f * 16 + (lane & 15)) * 40 + (lane >> 4) * 8];
#pragma unroll
        for (int i = 0; i < 4; ++i)
#pragma unroll
            for (int j = 0; j < 4; ++j)
                acc[i][j] = __builtin_amdgcn_mfma_f32_16x16x32_bf16(af[i], bfr[j], acc[i][j], 0, 0, 0);
    }

#pragma unroll
    for (int i = 0; i < 4; ++i) {
        const int gRow0 = tm * 128 + wr * 64 + i * 16 + ((lane >> 4) << 2);
#pragma unroll
        for (int j = 0; j < 4; ++j) {
            const int gCol = tn * 128 + wc * 64 + j * 16 + (lane & 15);
            f32x4 v = acc[i][j];
            if (EPI == 1) {
                const float bb2 = bias[gCol];
                const int hh = gCol >> 6, dd = gCol & 63;
                const int b = gRow0 >> 10, ll2 = gRow0 & 1023;
                unsigned short* C = (unsigned short*)Cout;
                short4v u;
                u[0] = (short)f2bf(v[0] + bb2);
                u[1] = (short)f2bf(v[1] + bb2);
                u[2] = (short)f2bf(v[2] + bb2);
                u[3] = (short)f2bf(v[3] + bb2);
                *(short4v*)(C + (size_t)hh * 524288 + ((size_t)b * 64 + dd) * 1024 + ll2) = u;
            } else if (EPI == 2) {
                const int b = gCol >> 6, dd = gCol & 63;
                unsigned short* X = (unsigned short*)Cout;
#pragma unroll
                for (int r = 0; r < 4; ++r)
                    X[((size_t)b * 1024 + gRow0 + r) * 1024 + bh * 64 + dd] = f2bf(v[r]);
            } else {
                const float bb2 = bias[gCol];
                float* O = (float*)Cout;
#pragma unroll
                for (int r = 0; r < 4; ++r)
                    O[(size_t)(gRow0 + r) * 1024 + gCol] = v[r] + bb2;
            }
        }
    }
}

// ---------------- in-place row LayerNorm over DM=1024 ----------------
__global__ __launch_bounds__(256) void ln_kernel(float* __restrict__ out,
                                                 const float* __restrict__ g,
                                                 const float* __restrict__ b) {
    __shared__ float red[8];
    const int row = blockIdx.x, t = threadIdx.x;
    float4* p = (float4*)(out + ((size_t)row << 10));
    float4 x = p[t];
    float s = x.x + x.y + x.z + x.w;
    float sq = x.x * x.x + x.y * x.y + x.z * x.z + x.w * x.w;
    s = waveSum(s);
    sq = waveSum(sq);
    if ((t & 63) == 0) { red[t >> 6] = s; red[4 + (t >> 6)] = sq; }
    __syncthreads();
    s = red[0] + red[1] + red[2] + red[3];
    sq = red[4] + red[5] + red[6] + red[7];
    const float mu = s * (1.f / 1024.f);
    const float var = sq * (1.f / 1024.f) - mu * mu;
    const float rinv = rsqrtf(var + 1e-5f);
    const float4 gg = ((const float4*)g)[t];
    const float4 bb = ((const float4*)b)[t];
    x.x = (x.x - mu) * rinv * gg.x + bb.x;
    x.y = (x.y - mu) * rinv * gg.y + bb.y;
    x.z = (x.z - mu) * rinv * gg.z + bb.z;
    x.w = (x.w - mu) * rinv * gg.w + bb.w;
    p[t] = x;
}

extern "C" void kernel_launch(void* const* d_in, const int* in_sizes, int n_in,
                              void* d_out, int out_size, void* d_ws, size_t ws_size,
                              hipStream_t stream) {
    // inputs: 0=q(unused) 1=k(unused) 2=v 3=posi_att 4=w_k(unused) 5=b_k(unused)
    //         6=w_v 7=b_v 8=w_fc 9=b_fc 10=ln_g 11=ln_b
    const float* v    = (const float*)d_in[2];
    const float* posi = (const float*)d_in[3];
    const float* w_v  = (const float*)d_in[6];
    const float* b_v  = (const float*)d_in[7];
    const float* w_fc = (const float*)d_in[8];
    const float* b_fc = (const float*)d_in[9];
    const float* ln_g = (const float*)d_in[10];
    const float* ln_b = (const float*)d_in[11];

    float* out = (float*)d_out;                       // [8, 1024, 1024] fp32
    float* attn_out = out + (size_t)NB * NL * NDM;    // [128, 1024, 1024] fp32

    // workspace layout (84 MB total)
    char* ws = (char*)d_ws;
    unsigned short* A_bf   = (unsigned short*)(ws);              // [16][1024][1024] bf16  32MB
    unsigned short* v_bf   = (unsigned short*)(ws + 33554432);   // [8192][1024]     bf16  16MB
    unsigned short* wv_bf  = (unsigned short*)(ws + 50331648);   // [1024][1024]     bf16   2MB
    unsigned short* wfc_bf = (unsigned short*)(ws + 52428800);   // [1024][1024]     bf16   2MB
    unsigned short* vvT    = (unsigned short*)(ws + 54525952);   // [16][512][1024]  bf16  16MB
    unsigned short* X      = (unsigned short*)(ws + 71303168);   // [8192][1024]     bf16  16MB

    cvt_bf16<<<8192, 256, 0, stream>>>(v, v_bf);
    cvt_bf16<<<1024, 256, 0, stream>>>(w_v, wv_bf);
    cvt_bf16<<<1024, 256, 0, stream>>>(w_fc, wfc_bf);

    softmax_rep<<<16384, 256, 0, stream>>>(posi, attn_out, A_bf);

    // vv[b,l,h,d] = v[b,l,:]@w_v[h*64+d,:] + b_v  -> stored as vvT[h][b*64+d][l]
    gemm_bt<1><<<dim3(8, 64, 1), 256, 0, stream>>>(v_bf, wv_bf, b_v, vvT, 8192, 1024, 1024);
    // ctx: per h: A[h] (1024x1024) @ vvT[h]^T (1024x512) -> X[(b*1024+q)][h*64+d]
    gemm_bt<2><<<dim3(4, 8, 16), 256, 0, stream>>>(A_bf, vvT, nullptr, X, 1024, 512, 1024);
    // out = X @ w_fc^T + b_fc  (fp32)
    gemm_bt<3><<<dim3(8, 64, 1), 256, 0, stream>>>(X, wfc_bf, b_fc, out, 8192, 1024, 1024);

    ln_kernel<<<8192, 256, 0, stream>>>(out, ln_g, ln_b);
}